// Round 8
// baseline (392.446 us; speedup 1.0000x reference)
//
#include <hip/hip_runtime.h>

#define B_ 2
#define L_ 2048
#define D_ 768
#define H_ 8
#define DK_ 64
#define DV_ 96
#define NPOS_ 32

typedef __attribute__((ext_vector_type(8))) __bf16 bf16x8;
typedef __attribute__((ext_vector_type(4))) float f32x4;

static __device__ __forceinline__ float bs2f(short s) {
    return (float)__builtin_bit_cast(__bf16, s);
}
static __device__ __forceinline__ short f2bs(float f) {
    return __builtin_bit_cast(short, (__bf16)f);
}

// ---------------------------------------------------------------------------
// prep: blocks 0..1055 transpose+convert all weights (wq/wk/wv packed into
// wqkvT[1792][768]); block 1056 builds sidx table + adjusted VU/VS tables:
// VU = 0.125*(suffix(v.wpos) - suffix(u.wpos))   [u-part corrects the q+u fold]
// sidx[d+2047]: s<17 -> d>0 (SU+SS), 17..33 -> d<0 (SU-SS), 34 -> d==0 (SU).
// ---------------------------------------------------------------------------
__global__ __launch_bounds__(256) void prep_kernel(
    const float* __restrict__ wq, const float* __restrict__ wk,
    const float* __restrict__ wv, const float* __restrict__ wo,
    const float* __restrict__ w1, const float* __restrict__ w2,
    const float* __restrict__ vparam, const float* __restrict__ uparam,
    const float* __restrict__ wpos,
    short* __restrict__ wqkvT, short* __restrict__ woT,
    short* __restrict__ w1T, short* __restrict__ w2T,
    unsigned char* __restrict__ sidx, float* __restrict__ VU, float* __restrict__ VS)
{
    __shared__ short T[64][66];
    __shared__ float vw[H_ * NPOS_];
    __shared__ float uw[H_ * NPOS_];
    int blk = blockIdx.x, tid = threadIdx.x;
    if (blk < 1056) {
        const float* W; short* Wt; int K, N, bx, by;
        if (blk < 96)       { W = wq; Wt = wqkvT;              K = 768;  N = 512;  int b = blk;       bx = b % 8;  by = b / 8; }
        else if (blk < 192) { W = wk; Wt = wqkvT + 512 * 768;  K = 768;  N = 512;  int b = blk - 96;  bx = b % 8;  by = b / 8; }
        else if (blk < 336) { W = wv; Wt = wqkvT + 1024 * 768; K = 768;  N = 768;  int b = blk - 192; bx = b % 12; by = b / 12; }
        else if (blk < 480) { W = wo; Wt = woT;                K = 768;  N = 768;  int b = blk - 336; bx = b % 12; by = b / 12; }
        else if (blk < 768) { W = w1; Wt = w1T;                K = 768;  N = 1536; int b = blk - 480; bx = b % 24; by = b / 24; }
        else                { W = w2; Wt = w2T;                K = 1536; N = 768;  int b = blk - 768; bx = b % 12; by = b / 12; }
        int n0 = bx << 6, k0 = by << 6;
        for (int idx = tid; idx < 4096; idx += 256) {
            int r = idx >> 6, c = idx & 63;
            T[c][r] = f2bs(W[(size_t)(k0 + r) * N + n0 + c]);
        }
        __syncthreads();
        for (int idx = tid; idx < 4096; idx += 256) {
            int r = idx >> 6, c = idx & 63;
            Wt[(size_t)(n0 + r) * K + k0 + c] = T[r][c];
        }
    } else {
        float pr = expf(logf((L_ + 1) / 2.0f) / (NPOS_ / 2));
        for (int idx = tid; idx < 4095; idx += 256) {
            int d = idx - 2047;
            int ad = d < 0 ? -d : d;
            int c = 0;
            for (int m = 1; m <= NPOS_ / 2; ++m) {
                float cw = powf(pr, (float)m);
                if (cw < (float)ad) c++;
            }
            sidx[idx] = (unsigned char)(d > 0 ? c : (d < 0 ? 17 + c : 34));
        }
        {
            int h = tid >> 5, n = tid & 31;
            float av = 0.f, au = 0.f;
            for (int d = 0; d < DK_; ++d) {
                float wp = wpos[(h * DK_ + d) * NPOS_ + n];
                av += vparam[h * DK_ + d] * wp;
                au += uparam[h * DK_ + d] * wp;
            }
            vw[tid] = av;
            uw[tid] = au;
        }
        __syncthreads();
        if (tid < H_ * 17) {
            int h = tid / 17, m = tid % 17;
            float su = 0.f, ss = 0.f;
            for (int t2 = m; t2 < 16; ++t2) {
                su += vw[h * NPOS_ + t2] - uw[h * NPOS_ + t2];
                ss += vw[h * NPOS_ + 16 + t2] - uw[h * NPOS_ + 16 + t2];
            }
            VU[h * 17 + m] = su * 0.125f;
            VS[h * 17 + m] = ss * 0.125f;
        }
    }
}

// ---------------------------------------------------------------------------
// RMSNorm (row of 768), fp32 in, bf16 out
// ---------------------------------------------------------------------------
__global__ __launch_bounds__(256) void rmsnorm_kernel(
    const float* __restrict__ x, const float* __restrict__ wgt, short* __restrict__ out)
{
    int row = blockIdx.x, tid = threadIdx.x;
    __shared__ float red[4];
    const float* xr = x + (size_t)row * D_;
    float ss = 0.f;
    for (int c = tid; c < D_; c += 256) { float f = xr[c]; ss += f * f; }
    for (int msk = 1; msk < 64; msk <<= 1) ss += __shfl_xor(ss, msk);
    if ((tid & 63) == 0) red[tid >> 6] = ss;
    __syncthreads();
    float tot = red[0] + red[1] + red[2] + red[3];
    float sc = rsqrtf(tot * (1.f / D_) + 1e-5f);
    for (int c = tid; c < D_; c += 256)
        out[(size_t)row * D_ + c] = f2bs(xr[c] * sc * wgt[c]);
}

// ---------------------------------------------------------------------------
// 64x64-tile bf16 MFMA GEMM (N=768 shapes: wo, FFN2)
// ---------------------------------------------------------------------------
__global__ __launch_bounds__(256) void gemm64(
    const short* __restrict__ A, const short* __restrict__ Bt,
    const float* __restrict__ bias, const float* __restrict__ resid,
    void* __restrict__ outp,
    int M, int N, int K, int act, int out_f32)
{
    __shared__ __align__(16) short Al[64 * 72];
    __shared__ __align__(16) short Bl[64 * 72];
    int tid = threadIdx.x;
    int w = tid >> 6, lane = tid & 63, quad = lane >> 4, t = lane & 15;
    int m0b = blockIdx.y << 6, n0b = blockIdx.x << 6;
    int wr = (w >> 1) << 5, wc = (w & 1) << 5;
    f32x4 acc[2][2] = {};
    for (int kb = 0; kb < K; kb += 64) {
        __syncthreads();
#pragma unroll
        for (int it = 0; it < 2; ++it) {
            int idx = tid + (it << 8);
            int r = idx >> 3, c8 = (idx & 7) << 3;
            *(bf16x8*)&Al[r * 72 + c8] = *(const bf16x8*)&A[(size_t)(m0b + r) * K + kb + c8];
            *(bf16x8*)&Bl[r * 72 + c8] = *(const bf16x8*)&Bt[(size_t)(n0b + r) * K + kb + c8];
        }
        __syncthreads();
#pragma unroll
        for (int ks = 0; ks < 2; ++ks) {
            bf16x8 af0 = *(bf16x8*)&Al[(wr + t) * 72 + (ks << 5) + (quad << 3)];
            bf16x8 af1 = *(bf16x8*)&Al[(wr + 16 + t) * 72 + (ks << 5) + (quad << 3)];
            bf16x8 bf0 = *(bf16x8*)&Bl[(wc + t) * 72 + (ks << 5) + (quad << 3)];
            bf16x8 bf1 = *(bf16x8*)&Bl[(wc + 16 + t) * 72 + (ks << 5) + (quad << 3)];
            acc[0][0] = __builtin_amdgcn_mfma_f32_16x16x32_bf16(af0, bf0, acc[0][0], 0, 0, 0);
            acc[0][1] = __builtin_amdgcn_mfma_f32_16x16x32_bf16(af0, bf1, acc[0][1], 0, 0, 0);
            acc[1][0] = __builtin_amdgcn_mfma_f32_16x16x32_bf16(af1, bf0, acc[1][0], 0, 0, 0);
            acc[1][1] = __builtin_amdgcn_mfma_f32_16x16x32_bf16(af1, bf1, acc[1][1], 0, 0, 0);
        }
    }
#pragma unroll
    for (int ms = 0; ms < 2; ++ms)
#pragma unroll
        for (int ns = 0; ns < 2; ++ns)
#pragma unroll
            for (int r = 0; r < 4; ++r) {
                int row = m0b + wr + (ms << 4) + (quad << 2) + r;
                int col = n0b + wc + (ns << 4) + t;
                float v2 = acc[ms][ns][r];
                if (bias) v2 += bias[col];
                if (act == 1) v2 = 0.5f * v2 * (1.f + erff(v2 * 0.70710678118654752f));
                if (resid) v2 += resid[(size_t)row * N + col];
                if (out_f32) ((float*)outp)[(size_t)row * N + col] = v2;
                else ((short*)outp)[(size_t)row * N + col] = f2bs(v2);
            }
}

// ---------------------------------------------------------------------------
// 128x128-tile bf16 MFMA GEMM (QKV & FFN1). uadd: if non-null, cols<512 get
// v = 0.125*(acc + uadd[col])  (fused q-scale + u-fold for QKV).
// ---------------------------------------------------------------------------
__global__ __launch_bounds__(256) void gemm128(
    const short* __restrict__ A, const short* __restrict__ Bt,
    const float* __restrict__ bias, const float* __restrict__ uadd,
    void* __restrict__ outp, int M, int N, int K, int act)
{
    __shared__ __align__(16) short Al[128 * 72];
    __shared__ __align__(16) short Bl[128 * 72];
    int tid = threadIdx.x;
    int w = tid >> 6, lane = tid & 63, quad = lane >> 4, t = lane & 15;
    int m0b = blockIdx.y << 7, n0b = blockIdx.x << 7;
    int wm = (w >> 1) << 6, wn = (w & 1) << 6;
    f32x4 acc[4][4] = {};
    for (int kb = 0; kb < K; kb += 64) {
        __syncthreads();
#pragma unroll
        for (int it = 0; it < 4; ++it) {
            int c = tid + (it << 8);
            int r = c >> 3, c8 = (c & 7) << 3;
            *(bf16x8*)&Al[r * 72 + c8] = *(const bf16x8*)&A[(size_t)(m0b + r) * K + kb + c8];
            *(bf16x8*)&Bl[r * 72 + c8] = *(const bf16x8*)&Bt[(size_t)(n0b + r) * K + kb + c8];
        }
        __syncthreads();
#pragma unroll
        for (int ks = 0; ks < 2; ++ks) {
            bf16x8 af[4], bf[4];
#pragma unroll
            for (int ms = 0; ms < 4; ++ms)
                af[ms] = *(bf16x8*)&Al[(wm + ms * 16 + t) * 72 + (ks << 5) + (quad << 3)];
#pragma unroll
            for (int ns = 0; ns < 4; ++ns)
                bf[ns] = *(bf16x8*)&Bl[(wn + ns * 16 + t) * 72 + (ks << 5) + (quad << 3)];
#pragma unroll
            for (int ms = 0; ms < 4; ++ms)
#pragma unroll
                for (int ns = 0; ns < 4; ++ns)
                    acc[ms][ns] = __builtin_amdgcn_mfma_f32_16x16x32_bf16(af[ms], bf[ns], acc[ms][ns], 0, 0, 0);
        }
    }
#pragma unroll
    for (int ms = 0; ms < 4; ++ms)
#pragma unroll
        for (int ns = 0; ns < 4; ++ns)
#pragma unroll
            for (int r = 0; r < 4; ++r) {
                int row = m0b + wm + ms * 16 + (quad << 2) + r;
                int col = n0b + wn + ns * 16 + t;
                float v2 = acc[ms][ns][r];
                if (uadd && col < 512) v2 = 0.125f * (v2 + uadd[col]);
                if (bias) v2 += bias[col];
                if (act == 1) v2 = 0.5f * v2 * (1.f + erff(v2 * 0.70710678118654752f));
                ((short*)outp)[(size_t)row * N + col] = f2bs(v2);
            }
}

// ---------------------------------------------------------------------------
// qsuf: per row, qw suffix sums folded with VU/VS into the final bias table
// Tg[row][h][35] (fp32, global). s<17: SU+SS, 17..33: SU-SS, 34: SU.
// ---------------------------------------------------------------------------
__global__ __launch_bounds__(256) void qsuf_kernel(
    const short* __restrict__ qkv, const float* __restrict__ wpos,
    const float* __restrict__ VU, const float* __restrict__ VS,
    float* __restrict__ Tg)
{
    __shared__ float qrow[512];
    __shared__ float qw[256];
    __shared__ float sU[136], sS[136];
    int row = blockIdx.x, tid = threadIdx.x;
    const short* base = qkv + (size_t)row * 1792;
    qrow[tid]       = bs2f(base[tid]);
    qrow[tid + 256] = bs2f(base[tid + 256]);
    __syncthreads();
    int h = tid >> 5, n = tid & 31;
    float acc = 0.f;
    for (int d = 0; d < DK_; ++d)
        acc += qrow[h * DK_ + d] * wpos[(h * DK_ + d) * NPOS_ + n];
    qw[tid] = acc;
    __syncthreads();
    if (tid < 136) {
        int hh = tid / 17, m = tid % 17;
        float su = 0.f, ss = 0.f;
        for (int t2 = m; t2 < 16; ++t2) { su += qw[hh * NPOS_ + t2]; ss += qw[hh * NPOS_ + 16 + t2]; }
        sU[tid] = su + VU[tid];
        sS[tid] = ss + VS[tid];
    }
    __syncthreads();
    if (tid < 280) {
        int h2 = tid / 35, s = tid % 35;
        int m = s < 17 ? s : (s < 34 ? s - 17 : 0);
        float su = sU[h2 * 17 + m], ss = sS[h2 * 17 + m];
        Tg[(size_t)row * 280 + tid] = s < 17 ? su + ss : (s < 34 ? su - ss : su);
    }
}

// ---------------------------------------------------------------------------
// vtrans: V section of qkv -> vT[bh][dv][j]  (per-head transposed V)
// Grid (32 j-tiles, 16 bh), block 256.
// ---------------------------------------------------------------------------
__global__ __launch_bounds__(256) void vtrans_kernel(
    const short* __restrict__ qkv, short* __restrict__ vT)
{
    __shared__ __align__(16) short T[64 * 104];
    int tid = threadIdx.x;
    int bh = blockIdx.y, b = bh >> 3, h = bh & 7;
    int j0 = blockIdx.x << 6;
#pragma unroll
    for (int it = 0; it < 3; ++it) {
        int idx = tid + (it << 8);
        int row = idx / 12, c8 = (idx % 12) << 3;
        *(bf16x8*)&T[row * 104 + c8] =
            *(const bf16x8*)&qkv[(size_t)(b * L_ + j0 + row) * 1792 + 1024 + h * DV_ + c8];
    }
    __syncthreads();
#pragma unroll
    for (int it = 0; it < 3; ++it) {
        int dv = (tid & 31) + (it << 5);
        int j8 = ((tid >> 5) & 7) << 3;
        bf16x8 o;
#pragma unroll
        for (int e = 0; e < 8; ++e) o[e] = __builtin_bit_cast(__bf16, T[(j8 + e) * 104 + dv]);
        *(bf16x8*)&vT[((size_t)bh * DV_ + dv) * L_ + j0 + j8] = o;
    }
}

// ---------------------------------------------------------------------------
// MFMA flash attention: 64-wide j-tiles, register-prefetched K/V staging,
// bias via L1 (sidx bytes + Tg floats), LDS 31.5 KB -> 4 blocks/CU.
// Grid: (L/64, B*H), 4 waves/block.
// ---------------------------------------------------------------------------
__global__ __launch_bounds__(256, 4) void flash_kernel(
    const short* __restrict__ qkv, const short* __restrict__ vT,
    const float* __restrict__ Tg, const unsigned char* __restrict__ sidx_g,
    short* __restrict__ ao)
{
    __shared__ __align__(16) short Kl[64 * 72];   // [j][d]
    __shared__ __align__(16) short Vt[96 * 72];   // [dv][j]
    __shared__ __align__(16) short Pl[64 * 72];   // [il][j]
    int tid = threadIdx.x, w = tid >> 6, lane = tid & 63, quad = lane >> 4, t = lane & 15;
    int bh = blockIdx.y, b = bh >> 3, h = bh & 7;
    int i0 = blockIdx.x << 6;

    int iq = i0 + w * 16 + t;
    const short* qbase = qkv + (size_t)(b * L_ + iq) * 1792 + h * DK_;
    bf16x8 qf0 = *(const bf16x8*)(qbase + (quad << 3));
    bf16x8 qf1 = *(const bf16x8*)(qbase + 32 + (quad << 3));

    f32x4 O[6] = {};
    float lsum[4] = {0.f, 0.f, 0.f, 0.f};

    // prefetch index mapping
    int kr = tid >> 3, kc = (tid & 7) << 3;            // K rows kr(+32), cols kc..kc+7
    int vdv = tid & 31, vj8 = ((tid >> 5) & 7) << 3;   // V rows vdv(+32it), j-chunk vj8
    bf16x8 kpre[2], vpre[3];
    {
        const short* kb0 = &qkv[(size_t)(b * L_ + kr) * 1792 + 512 + h * DK_ + kc];
        kpre[0] = *(const bf16x8*)kb0;
        kpre[1] = *(const bf16x8*)(kb0 + (size_t)32 * 1792);
#pragma unroll
        for (int it = 0; it < 3; ++it)
            vpre[it] = *(const bf16x8*)&vT[((size_t)bh * DV_ + vdv + (it << 5)) * L_ + vj8];
    }

    for (int j0 = 0; j0 < L_; j0 += 64) {
        __syncthreads();
        *(bf16x8*)&Kl[kr * 72 + kc] = kpre[0];
        *(bf16x8*)&Kl[(kr + 32) * 72 + kc] = kpre[1];
#pragma unroll
        for (int it = 0; it < 3; ++it)
            *(bf16x8*)&Vt[(vdv + (it << 5)) * 72 + vj8] = vpre[it];
        {
            int jn = (j0 + 64 < L_) ? j0 + 64 : 0;
            const short* kb0 = &qkv[(size_t)(b * L_ + jn + kr) * 1792 + 512 + h * DK_ + kc];
            kpre[0] = *(const bf16x8*)kb0;
            kpre[1] = *(const bf16x8*)(kb0 + (size_t)32 * 1792);
#pragma unroll
            for (int it = 0; it < 3; ++it)
                vpre[it] = *(const bf16x8*)&vT[((size_t)bh * DV_ + vdv + (it << 5)) * L_ + jn + vj8];
        }
        __syncthreads();

        f32x4 S[4];
#pragma unroll
        for (int ct = 0; ct < 4; ++ct) {
            bf16x8 b0 = *(bf16x8*)&Kl[(ct * 16 + t) * 72 + (quad << 3)];
            bf16x8 b1 = *(bf16x8*)&Kl[(ct * 16 + t) * 72 + 32 + (quad << 3)];
            f32x4 z = {};
            z = __builtin_amdgcn_mfma_f32_16x16x32_bf16(qf0, b0, z, 0, 0, 0);
            S[ct] = __builtin_amdgcn_mfma_f32_16x16x32_bf16(qf1, b1, z, 0, 0, 0);
        }
#pragma unroll
        for (int r = 0; r < 4; ++r) {
            int il = w * 16 + (quad << 2) + r;
            int i = i0 + il;
            const float* tg = Tg + ((size_t)(b * L_ + i) * 8 + h) * 35;
            int based = j0 - i + 2047 + t;
#pragma unroll
            for (int ct = 0; ct < 4; ++ct) {
                int s = sidx_g[based + ct * 16];
                float p = __expf(S[ct][r] + tg[s]);
                short pb = f2bs(p);
                lsum[r] += bs2f(pb);
                Pl[il * 72 + ct * 16 + t] = pb;
            }
        }
        // PV: same-wave LDS round-trip (each wave reads only its own P rows)
#pragma unroll
        for (int ks = 0; ks < 2; ++ks) {
            bf16x8 pa = *(bf16x8*)&Pl[(w * 16 + t) * 72 + (ks << 5) + (quad << 3)];
#pragma unroll
            for (int dv = 0; dv < 6; ++dv) {
                bf16x8 vb = *(bf16x8*)&Vt[(dv * 16 + t) * 72 + (ks << 5) + (quad << 3)];
                O[dv] = __builtin_amdgcn_mfma_f32_16x16x32_bf16(pa, vb, O[dv], 0, 0, 0);
            }
        }
    }
#pragma unroll
    for (int r = 0; r < 4; ++r) {
        float lr = lsum[r];
        lr += __shfl_xor(lr, 1);
        lr += __shfl_xor(lr, 2);
        lr += __shfl_xor(lr, 4);
        lr += __shfl_xor(lr, 8);
        float inv = 1.f / lr;
        int i = i0 + w * 16 + (quad << 2) + r;
        size_t base = (size_t)(b * L_ + i) * D_ + h * DV_;
#pragma unroll
        for (int dv = 0; dv < 6; ++dv) ao[base + dv * 16 + t] = f2bs(O[dv][r] * inv);
    }
}

// ---------------------------------------------------------------------------
extern "C" void kernel_launch(void* const* d_in, const int* in_sizes, int n_in,
                              void* d_out, int out_size, void* d_ws, size_t ws_size,
                              hipStream_t stream)
{
    const float* x    = (const float*)d_in[0];
    const float* n1w  = (const float*)d_in[1];
    const float* n2w  = (const float*)d_in[2];
    const float* wq   = (const float*)d_in[3];
    const float* wk   = (const float*)d_in[4];
    const float* wv   = (const float*)d_in[5];
    const float* wo   = (const float*)d_in[6];
    const float* bo   = (const float*)d_in[7];
    const float* up   = (const float*)d_in[8];
    const float* vp   = (const float*)d_in[9];
    const float* wpos = (const float*)d_in[10];
    const float* w1   = (const float*)d_in[11];
    const float* b1   = (const float*)d_in[12];
    const float* w2   = (const float*)d_in[13];
    const float* b2   = (const float*)d_in[14];

    char* ws = (char*)d_ws;
    short* h1   = (short*)(ws + 0);         // [4096,768] bf16
    short* qkv  = (short*)(ws + 6291456);   // [4096,1792] bf16, ends 20971520
    float* Tg   = (float*)(ws + 20971520);  // [4096,8,35] f32, ends 25559040
    float* VUg  = (float*)(ws + 25559040);
    float* VSg  = (float*)(ws + 25560064);
    unsigned char* sidx = (unsigned char*)(ws + 25561088);  // [4096]
    short* ao   = (short*)(ws + 25569280);  // [4096,768] bf16
    float* x2   = (float*)(ws + 31860736);  // [4096,768] f32, ends 44443648
    short* vT   = (short*)(ws + 31860736);  // [16,96,2048] bf16 overlays x2 (dead before wo-gemm)
    short* wqkvT= (short*)(ws + 44443648);  // [1792,768] bf16, ends 47196160
    short* woT  = (short*)(ws + 47196160);  // [768,768]
    short* w1T  = (short*)(ws + 48375808);  // [1536,768]
    short* w2T  = (short*)(ws + 50735104);  // [768,1536], ends 53094400
    short* f1   = (short*)(ws + 0);         // [4096,1536] overlays h1+qkv head (dead)
    short* h2n  = (short*)(ws + 14680064);  // [4096,768] overlays qkv tail (dead)

    prep_kernel<<<1057, 256, 0, stream>>>(wq, wk, wv, wo, w1, w2, vp, up, wpos,
                                          wqkvT, woT, w1T, w2T, sidx, VUg, VSg);
    rmsnorm_kernel<<<4096, 256, 0, stream>>>(x, n1w, h1);
    gemm128<<<dim3(14, 32), 256, 0, stream>>>(h1, wqkvT, nullptr, up, qkv, 4096, 1792, 768, 0);
    qsuf_kernel<<<4096, 256, 0, stream>>>(qkv, wpos, VUg, VSg, Tg);
    vtrans_kernel<<<dim3(32, 16), 256, 0, stream>>>(qkv, vT);
    flash_kernel<<<dim3(32, 16), 256, 0, stream>>>(qkv, vT, Tg, sidx, ao);
    gemm64<<<dim3(12, 64), 256, 0, stream>>>(ao, woT, bo, x, x2, 4096, 768, 768, 0, 1);
    rmsnorm_kernel<<<4096, 256, 0, stream>>>(x2, n2w, h2n);
    gemm128<<<dim3(12, 32), 256, 0, stream>>>(h2n, w1T, b1, nullptr, f1, 4096, 1536, 768, 1);
    gemm64<<<dim3(12, 64), 256, 0, stream>>>(f1, w2T, b2, x2, d_out, 4096, 768, 1536, 0, 1);
}